// Round 2
// baseline (1008.546 us; speedup 1.0000x reference)
//
#include <hip/hip_runtime.h>
#include <math.h>

#define D 4096
#define H 64
#define S 64
#define EPS 1e-5f
#define NB 1024   // grid size; co-residency guaranteed at 4 blocks/CU

__device__ __forceinline__ float wave_reduce_sum(float v) {
#pragma unroll
    for (int off = 32; off > 0; off >>= 1) v += __shfl_down(v, off, 64);
    return v;
}

// Manual grid barrier: cnt self-resets, gen increments per barrier.
// gen/cnt zeroed by a stream-ordered memset before each launch.
__device__ __forceinline__ void grid_barrier(unsigned* cnt, unsigned* gen) {
    __threadfence();            // release: make this thread's stores agent-visible
    __syncthreads();
    if (threadIdx.x == 0) {
        unsigned g = __hip_atomic_load(gen, __ATOMIC_RELAXED, __HIP_MEMORY_SCOPE_AGENT);
        unsigned t = __hip_atomic_fetch_add(cnt, 1u, __ATOMIC_ACQ_REL, __HIP_MEMORY_SCOPE_AGENT);
        if (t == NB - 1u) {
            __hip_atomic_store(cnt, 0u, __ATOMIC_RELAXED, __HIP_MEMORY_SCOPE_AGENT);
            __hip_atomic_fetch_add(gen, 1u, __ATOMIC_RELEASE, __HIP_MEMORY_SCOPE_AGENT);
        } else {
            int guard = 0;
            while (__hip_atomic_load(gen, __ATOMIC_ACQUIRE, __HIP_MEMORY_SCOPE_AGENT) == g
                   && ++guard < (1 << 28)) { }
        }
    }
    __syncthreads();
    __threadfence();            // acquire side
}

__global__ __launch_bounds__(256, 4) void k_mega(
    const float* __restrict__ x, const float* __restrict__ state1,
    const float* __restrict__ state2,
    const float* __restrict__ tmk, const float* __restrict__ tmv,
    const float* __restrict__ tmr, const float* __restrict__ tmg,
    const float* __restrict__ tdecay, const float* __restrict__ tfirst,
    const float* __restrict__ Wr, const float* __restrict__ Wk,
    const float* __restrict__ Wv, const float* __restrict__ Wg,
    const float* __restrict__ Wo,
    const float* __restrict__ ln1w, const float* __restrict__ ln1b,
    const float* __restrict__ lnxw, const float* __restrict__ lnxb,
    float* __restrict__ out, float* __restrict__ state1_out,
    float* __restrict__ state2_out, float* __restrict__ rkvg,
    float* __restrict__ y, unsigned* __restrict__ bar)
{
    __shared__ float4 smix[1024];     // this block's mix vector [D]
    __shared__ float red[8];
    __shared__ float mb[2];
    __shared__ float part[4][64];

    const int tid = threadIdx.x;
    const int wave = tid >> 6, lane = tid & 63;
    const int gb = blockIdx.x;        // 0..1023
    const int m = gb >> 8;            // matrix: 0=r 1=k 2=v 3=g
    const int R = (gb & 255) * 16;    // this block's 16 rows

    // ---------------- Phase A: LayerNorm(x) + build mix_m in LDS ----------------
    float4 x4[4];
    float s = 0.f, sq = 0.f;
#pragma unroll
    for (int i = 0; i < 4; ++i) {
        x4[i] = ((const float4*)x)[tid + 256 * i];
        s  += (x4[i].x + x4[i].y) + (x4[i].z + x4[i].w);
        sq += x4[i].x * x4[i].x + x4[i].y * x4[i].y
            + x4[i].z * x4[i].z + x4[i].w * x4[i].w;
    }
    s = wave_reduce_sum(s);
    sq = wave_reduce_sum(sq);
    if (lane == 0) { red[wave] = s; red[4 + wave] = sq; }
    __syncthreads();
    if (tid == 0) {
        float ts = red[0] + red[1] + red[2] + red[3];
        float tq = red[4] + red[5] + red[6] + red[7];
        float mmean = ts / (float)D;
        float var = tq / (float)D - mmean * mmean;
        mb[0] = mmean; mb[1] = rsqrtf(var + EPS);
    }
    __syncthreads();
    const float mmean = mb[0], rs = mb[1];
    const float* tm = (m == 0) ? tmr : (m == 1) ? tmk : (m == 2) ? tmv : tmg;
#pragma unroll
    for (int i = 0; i < 4; ++i) {
        const int idx = tid + 256 * i;
        const float4 w4 = ((const float4*)ln1w)[idx];
        const float4 b4 = ((const float4*)ln1b)[idx];
        const float4 s1 = ((const float4*)state1)[idx];
        const float4 t4 = ((const float4*)tm)[idx];
        float4 xx;
        xx.x = (x4[i].x - mmean) * rs * w4.x + b4.x;
        xx.y = (x4[i].y - mmean) * rs * w4.y + b4.y;
        xx.z = (x4[i].z - mmean) * rs * w4.z + b4.z;
        xx.w = (x4[i].w - mmean) * rs * w4.w + b4.w;
        if (gb == 0) ((float4*)state1_out)[idx] = xx;
        float4 o;
        o.x = s1.x + (xx.x - s1.x) * t4.x;
        o.y = s1.y + (xx.y - s1.y) * t4.y;
        o.z = s1.z + (xx.z - s1.z) * t4.z;
        o.w = s1.w + (xx.w - s1.w) * t4.w;
        smix[idx] = o;
    }
    __syncthreads();

    // ---------------- Phase B: GEMV, 4 consecutive rows per wave ----------------
    const float* W = (m == 0) ? Wr : (m == 1) ? Wk : (m == 2) ? Wv : Wg;
    const int r0 = R + wave * 4;
    const float4* wp = (const float4*)W + (size_t)r0 * 1024;
    float a0 = 0.f, a1 = 0.f, a2 = 0.f, a3 = 0.f;
#pragma unroll
    for (int c0 = 0; c0 < 16; c0 += 4) {
        float4 w0[4], w1[4], w2[4], w3[4];
#pragma unroll
        for (int c = 0; c < 4; ++c) w0[c] = wp[(c0 + c) * 64 + lane];
#pragma unroll
        for (int c = 0; c < 4; ++c) w1[c] = wp[1024 + (c0 + c) * 64 + lane];
#pragma unroll
        for (int c = 0; c < 4; ++c) w2[c] = wp[2048 + (c0 + c) * 64 + lane];
#pragma unroll
        for (int c = 0; c < 4; ++c) w3[c] = wp[3072 + (c0 + c) * 64 + lane];
#pragma unroll
        for (int c = 0; c < 4; ++c) {
            const float4 xv = smix[(c0 + c) * 64 + lane];
            a0 += w0[c].x * xv.x + w0[c].y * xv.y + w0[c].z * xv.z + w0[c].w * xv.w;
            a1 += w1[c].x * xv.x + w1[c].y * xv.y + w1[c].z * xv.z + w1[c].w * xv.w;
            a2 += w2[c].x * xv.x + w2[c].y * xv.y + w2[c].z * xv.z + w2[c].w * xv.w;
            a3 += w3[c].x * xv.x + w3[c].y * xv.y + w3[c].z * xv.z + w3[c].w * xv.w;
        }
    }
    a0 = wave_reduce_sum(a0);
    a1 = wave_reduce_sum(a1);
    a2 = wave_reduce_sum(a2);
    a3 = wave_reduce_sum(a3);
    if (lane == 0) {
        float* dst = rkvg + m * D + r0;
        dst[0] = a0; dst[1] = a1; dst[2] = a2; dst[3] = a3;
    }

    grid_barrier(bar, bar + 1);

    // ---------------- Phase C: per-head wkv / state2 / instance-norm / gate ----
    if (gb < H) {
        const int h = gb, j = lane;
        const int base = h * S;
        const float rj  = rkvg[base + j];
        const float kj  = rkvg[D + base + j];
        const float vj  = rkvg[2 * D + base + j];
        const float tfj = tfirst[base + j];
        const float tdj = tdecay[base + j];
        const float* s2 = state2 + (size_t)h * S * S;
        float* s2o = state2_out + (size_t)h * S * S;
        float sv[16];
#pragma unroll
        for (int ii = 0; ii < 16; ++ii) sv[ii] = s2[(wave * 16 + ii) * S + j];
        float wkv = 0.f;
#pragma unroll
        for (int ii = 0; ii < 16; ++ii) {
            const int i = wave * 16 + ii;
            const float ri  = __shfl(rj, i, 64);
            const float ki  = __shfl(kj, i, 64);
            const float tfi = __shfl(tfj, i, 64);
            const float tdi = __shfl(tdj, i, 64);
            const float kv = ki * vj;
            wkv += ri * (kv * tfi + sv[ii]);
            s2o[i * S + j] = kv + sv[ii] * tdi;
        }
        part[wave][j] = wkv;
        __syncthreads();
        if (wave == 0) {
            const float w0 = part[0][j] + part[1][j] + part[2][j] + part[3][j];
            float sum = w0, sq2 = w0 * w0;
#pragma unroll
            for (int off = 1; off < 64; off <<= 1) {
                sum += __shfl_xor(sum, off, 64);
                sq2 += __shfl_xor(sq2, off, 64);
            }
            const float mu = sum / (float)S;
            const float var = sq2 / (float)S - mu * mu;
            const float xn = (w0 - mu) * rsqrtf(var + EPS);
            const float gj = rkvg[3 * D + base + j];
            const float gate = gj / (1.f + expf(-gj));
            y[base + j] = (xn * lnxw[base + j] + lnxb[base + j]) * gate;
        }
    }

    grid_barrier(bar, bar + 1);

    // ---------------- Phase D: out = x + Wo @ y ; one row per wave --------------
    const int row = gb * 4 + wave;    // 0..4095
    const float4* wo = (const float4*)Wo + (size_t)row * 1024;
    const float4* y4 = (const float4*)y;
    float acc = 0.f;
#pragma unroll 4
    for (int c = 0; c < 16; ++c) {
        const int o = c * 64 + lane;
        const float4 yv = y4[o];
        const float4 wv = wo[o];
        acc += wv.x * yv.x + wv.y * yv.y + wv.z * yv.z + wv.w * yv.w;
    }
    acc = wave_reduce_sum(acc);
    if (lane == 0) out[row] = x[row] + acc;
}

extern "C" void kernel_launch(void* const* d_in, const int* in_sizes, int n_in,
                              void* d_out, int out_size, void* d_ws, size_t ws_size,
                              hipStream_t stream) {
    const float* x      = (const float*)d_in[0];
    const float* state1 = (const float*)d_in[1];
    const float* state2 = (const float*)d_in[2];
    const float* tmk    = (const float*)d_in[3];
    const float* tmv    = (const float*)d_in[4];
    const float* tmr    = (const float*)d_in[5];
    const float* tmg    = (const float*)d_in[6];
    const float* tdecay = (const float*)d_in[7];
    const float* tfirst = (const float*)d_in[8];
    const float* Wr     = (const float*)d_in[9];
    const float* Wk     = (const float*)d_in[10];
    const float* Wv     = (const float*)d_in[11];
    const float* Wg     = (const float*)d_in[12];
    const float* Wo     = (const float*)d_in[13];
    const float* ln1w   = (const float*)d_in[14];
    const float* ln1b   = (const float*)d_in[15];
    const float* lnxw   = (const float*)d_in[16];
    const float* lnxb   = (const float*)d_in[17];

    float* out        = (float*)d_out;        // [D]
    float* state1_out = out + D;              // [D]
    float* state2_out = out + 2 * D;          // [H*S*S]

    float* rkvg = (float*)d_ws;               // [4*D]
    float* y    = rkvg + 4 * D;               // [D]
    unsigned* bar = (unsigned*)(y + D);       // [2] barrier cnt/gen

    // Zero barrier state (stream-ordered; graph-capture safe, harness uses same API)
    hipMemsetAsync((void*)bar, 0, 2 * sizeof(unsigned), stream);

    hipLaunchKernelGGL(k_mega, dim3(NB), dim3(256), 0, stream,
                       x, state1, state2, tmk, tmv, tmr, tmg, tdecay, tfirst,
                       Wr, Wk, Wv, Wg, Wo, ln1w, ln1b, lnxw, lnxb,
                       out, state1_out, state2_out, rkvg, y, bar);
}

// Round 3
// 321.644 us; speedup vs baseline: 3.1356x; 3.1356x over previous
//
#include <hip/hip_runtime.h>
#include <math.h>

#define D 4096
#define H 64
#define S 64
#define EPS 1e-5f

__device__ __forceinline__ float wave_reduce_sum(float v) {
#pragma unroll
    for (int off = 32; off > 0; off >>= 1) v += __shfl_down(v, off, 64);
    return v;
}

// ---------------- Kernel 1: LayerNorm(x) -> xx; write state1_out; build 4 mix vectors
__global__ __launch_bounds__(1024) void k_ln_mix(
    const float* __restrict__ x, const float* __restrict__ state1,
    const float* __restrict__ tmk, const float* __restrict__ tmv,
    const float* __restrict__ tmr, const float* __restrict__ tmg,
    const float* __restrict__ ln1w, const float* __restrict__ ln1b,
    float* __restrict__ state1_out, float* __restrict__ mix /* [4][D]: r,k,v,g */) {
    __shared__ float red[32];
    __shared__ float mb[2];
    const int tid = threadIdx.x;
    const float4 xv = ((const float4*)x)[tid];
    float s = (xv.x + xv.y) + (xv.z + xv.w);
    float sq = (xv.x * xv.x + xv.y * xv.y) + (xv.z * xv.z + xv.w * xv.w);
    s = wave_reduce_sum(s);
    sq = wave_reduce_sum(sq);
    const int wave = tid >> 6, lane = tid & 63;
    if (lane == 0) { red[wave] = s; red[16 + wave] = sq; }
    __syncthreads();
    if (tid == 0) {
        float ts = 0.f, tq = 0.f;
        for (int i = 0; i < 16; ++i) { ts += red[i]; tq += red[16 + i]; }
        float m = ts / (float)D;
        float var = tq / (float)D - m * m;
        mb[0] = m;
        mb[1] = rsqrtf(var + EPS);
    }
    __syncthreads();
    const float m = mb[0], rs = mb[1];
    const float4 w4 = ((const float4*)ln1w)[tid];
    const float4 b4 = ((const float4*)ln1b)[tid];
    float4 xx;
    xx.x = (xv.x - m) * rs * w4.x + b4.x;
    xx.y = (xv.y - m) * rs * w4.y + b4.y;
    xx.z = (xv.z - m) * rs * w4.z + b4.z;
    xx.w = (xv.w - m) * rs * w4.w + b4.w;
    ((float4*)state1_out)[tid] = xx;
    const float4 s1 = ((const float4*)state1)[tid];
    float4 d;
    d.x = xx.x - s1.x; d.y = xx.y - s1.y; d.z = xx.z - s1.z; d.w = xx.w - s1.w;
    const float4 tr = ((const float4*)tmr)[tid];
    const float4 tk = ((const float4*)tmk)[tid];
    const float4 tv = ((const float4*)tmv)[tid];
    const float4 tg = ((const float4*)tmg)[tid];
    float4 o;
    o.x = s1.x + d.x * tr.x; o.y = s1.y + d.y * tr.y; o.z = s1.z + d.z * tr.z; o.w = s1.w + d.w * tr.w;
    ((float4*)mix)[tid] = o;
    o.x = s1.x + d.x * tk.x; o.y = s1.y + d.y * tk.y; o.z = s1.z + d.z * tk.z; o.w = s1.w + d.w * tk.w;
    ((float4*)mix)[1024 + tid] = o;
    o.x = s1.x + d.x * tv.x; o.y = s1.y + d.y * tv.y; o.z = s1.z + d.z * tv.z; o.w = s1.w + d.w * tv.w;
    ((float4*)mix)[2048 + tid] = o;
    o.x = s1.x + d.x * tg.x; o.y = s1.y + d.y * tg.y; o.z = s1.z + d.z * tg.z; o.w = s1.w + d.w * tg.w;
    ((float4*)mix)[3072 + tid] = o;
}

// ---------------- Kernel 2: fused 4x GEMV (Wr,Wk,Wv,Wg) @ their mixes -> rkvg[4][D]
// 2 rows per wave. Ping-pong register pipeline: prefetch chunk s+1 (8 float4)
// while consuming chunk s, fully unrolled, never draining the load queue.
__global__ __launch_bounds__(256) void k_gemv4(
    const float* __restrict__ Wr, const float* __restrict__ Wk,
    const float* __restrict__ Wv, const float* __restrict__ Wg,
    const float* __restrict__ mix, float* __restrict__ rkvg) {
    __shared__ float4 smix[1024];
    const int wave = threadIdx.x >> 6, lane = threadIdx.x & 63;
    const int wg = blockIdx.x * 4 + wave;      // 0..8191
    const int m = wg >> 11;                    // 2048 waves per matrix
    const int r0 = (wg & 2047) * 2;            // row pair within matrix
    const float* W = (m == 0) ? Wr : (m == 1) ? Wk : (m == 2) ? Wv : Wg;
    const float4* vx = (const float4*)mix + (m << 10);
#pragma unroll
    for (int t = 0; t < 4; ++t) smix[t * 256 + threadIdx.x] = vx[t * 256 + threadIdx.x];
    const float4* w0p = (const float4*)W + (size_t)r0 * 1024;
    const float4* w1p = w0p + 1024;

    float4 A0[4], A1[4], B0[4], B1[4];   // ping (A) / pong (B) chunks for row0/row1
    // prologue: chunk 0 -> A  (issued before the barrier; independent of LDS)
#pragma unroll
    for (int u = 0; u < 4; ++u) A0[u] = w0p[u * 64 + lane];
#pragma unroll
    for (int u = 0; u < 4; ++u) A1[u] = w1p[u * 64 + lane];
    __syncthreads();
    float a0 = 0.f, a1 = 0.f, b0 = 0.f, b1 = 0.f;

#define GSTEP(s, C0, C1, N0, N1, LAST)                                     \
    {                                                                      \
        if (!(LAST)) {                                                     \
            _Pragma("unroll")                                              \
            for (int u = 0; u < 4; ++u) N0[u] = w0p[(((s) + 1) * 4 + u) * 64 + lane]; \
            _Pragma("unroll")                                              \
            for (int u = 0; u < 4; ++u) N1[u] = w1p[(((s) + 1) * 4 + u) * 64 + lane]; \
        }                                                                  \
        _Pragma("unroll")                                                  \
        for (int u = 0; u < 4; ++u) {                                      \
            const float4 xv = smix[((s) * 4 + u) * 64 + lane];             \
            a0 += C0[u].x * xv.x + C0[u].y * xv.y;                         \
            a1 += C0[u].z * xv.z + C0[u].w * xv.w;                         \
            b0 += C1[u].x * xv.x + C1[u].y * xv.y;                         \
            b1 += C1[u].z * xv.z + C1[u].w * xv.w;                         \
        }                                                                  \
    }

    GSTEP(0, A0, A1, B0, B1, false)
    GSTEP(1, B0, B1, A0, A1, false)
    GSTEP(2, A0, A1, B0, B1, false)
    GSTEP(3, B0, B1, A0, A1, true)
#undef GSTEP

    float a = wave_reduce_sum(a0 + a1);
    float b = wave_reduce_sum(b0 + b1);
    if (lane == 0) {
        rkvg[m * D + r0] = a;
        rkvg[m * D + r0 + 1] = b;
    }
}

// ---------------- Kernel 3: per-head kv/wkv/state2 decay + instance norm + SiLU gate -> y
__global__ __launch_bounds__(1024) void k_heads(
    const float* __restrict__ rkvg, const float* __restrict__ state2,
    const float* __restrict__ tdecay, const float* __restrict__ tfirst,
    const float* __restrict__ lnxw, const float* __restrict__ lnxb,
    float* __restrict__ state2_out, float* __restrict__ y) {
    __shared__ float part[16][64];
    const int h = blockIdx.x;
    const int wave = threadIdx.x >> 6, j = threadIdx.x & 63;
    const int base = h * S;
    const float rj = rkvg[base + j];
    const float kj = rkvg[D + base + j];
    const float vj = rkvg[2 * D + base + j];
    const float tfj = tfirst[base + j];
    const float tdj = tdecay[base + j];
    const float* s2 = state2 + (size_t)h * S * S;
    float* s2o = state2_out + (size_t)h * S * S;
    float sv[4];
#pragma unroll
    for (int ii = 0; ii < 4; ++ii) sv[ii] = s2[(wave * 4 + ii) * S + j];
    float wkv = 0.f;
#pragma unroll
    for (int ii = 0; ii < 4; ++ii) {
        const int i = wave * 4 + ii;
        float ri = __shfl(rj, i, 64);
        float ki = __shfl(kj, i, 64);
        float tfi = __shfl(tfj, i, 64);
        float tdi = __shfl(tdj, i, 64);
        float kv = ki * vj;
        wkv += ri * (kv * tfi + sv[ii]);
        s2o[i * S + j] = kv + sv[ii] * tdi;
    }
    part[wave][j] = wkv;
    __syncthreads();
    if (wave == 0) {
        float w0 = 0.f;
#pragma unroll
        for (int t = 0; t < 16; ++t) w0 += part[t][j];
        float sum = w0, sq = w0 * w0;
#pragma unroll
        for (int off = 1; off < 64; off <<= 1) {
            sum += __shfl_xor(sum, off, 64);
            sq += __shfl_xor(sq, off, 64);
        }
        float mu = sum / (float)S;
        float var = sq / (float)S - mu * mu;
        float xn = (w0 - mu) * rsqrtf(var + EPS);
        float gj = rkvg[3 * D + base + j];
        float gate = gj / (1.f + expf(-gj));
        y[base + j] = (xn * lnxw[base + j] + lnxb[base + j]) * gate;
    }
}

// ---------------- Kernel 4: out = x + Wo @ y ; 1 row per wave, ping-pong pipeline
__global__ __launch_bounds__(256) void k_out(
    const float* __restrict__ Wo, const float* __restrict__ y,
    const float* __restrict__ x, float* __restrict__ out) {
    __shared__ float4 sy[1024];
    const int wave = threadIdx.x >> 6, lane = threadIdx.x & 63;
    const int row = blockIdx.x * 4 + wave;     // 0..4095
    const float4* vy = (const float4*)y;
#pragma unroll
    for (int t = 0; t < 4; ++t) sy[t * 256 + threadIdx.x] = vy[t * 256 + threadIdx.x];
    const float4* wp = (const float4*)Wo + (size_t)row * 1024;

    float4 A[4], B[4];
#pragma unroll
    for (int u = 0; u < 4; ++u) A[u] = wp[u * 64 + lane];
    __syncthreads();
    float a0 = 0.f, a1 = 0.f;

#define OSTEP(s, C, N, LAST)                                               \
    {                                                                      \
        if (!(LAST)) {                                                     \
            _Pragma("unroll")                                              \
            for (int u = 0; u < 4; ++u) N[u] = wp[(((s) + 1) * 4 + u) * 64 + lane]; \
        }                                                                  \
        _Pragma("unroll")                                                  \
        for (int u = 0; u < 4; ++u) {                                      \
            const float4 xv = sy[((s) * 4 + u) * 64 + lane];               \
            a0 += C[u].x * xv.x + C[u].y * xv.y;                           \
            a1 += C[u].z * xv.z + C[u].w * xv.w;                           \
        }                                                                  \
    }

    OSTEP(0, A, B, false)
    OSTEP(1, B, A, false)
    OSTEP(2, A, B, false)
    OSTEP(3, B, A, true)
#undef OSTEP

    float a = wave_reduce_sum(a0 + a1);
    if (lane == 0) out[row] = x[row] + a;
}

extern "C" void kernel_launch(void* const* d_in, const int* in_sizes, int n_in,
                              void* d_out, int out_size, void* d_ws, size_t ws_size,
                              hipStream_t stream) {
    const float* x      = (const float*)d_in[0];
    const float* state1 = (const float*)d_in[1];
    const float* state2 = (const float*)d_in[2];
    const float* tmk    = (const float*)d_in[3];
    const float* tmv    = (const float*)d_in[4];
    const float* tmr    = (const float*)d_in[5];
    const float* tmg    = (const float*)d_in[6];
    const float* tdecay = (const float*)d_in[7];
    const float* tfirst = (const float*)d_in[8];
    const float* Wr     = (const float*)d_in[9];
    const float* Wk     = (const float*)d_in[10];
    const float* Wv     = (const float*)d_in[11];
    const float* Wg     = (const float*)d_in[12];
    const float* Wo     = (const float*)d_in[13];
    const float* ln1w   = (const float*)d_in[14];
    const float* ln1b   = (const float*)d_in[15];
    const float* lnxw   = (const float*)d_in[16];
    const float* lnxb   = (const float*)d_in[17];

    float* out        = (float*)d_out;        // [D]
    float* state1_out = out + D;              // [D]
    float* state2_out = out + 2 * D;          // [H*S*S]

    float* mix  = (float*)d_ws;               // [4*D] (r,k,v,g order)
    float* rkvg = mix + 4 * D;                // [4*D]
    float* y    = rkvg + 4 * D;               // [D]

    k_ln_mix<<<1, 1024, 0, stream>>>(x, state1, tmk, tmv, tmr, tmg, ln1w, ln1b,
                                     state1_out, mix);
    k_gemv4<<<2048, 256, 0, stream>>>(Wr, Wk, Wv, Wg, mix, rkvg);
    k_heads<<<64, 1024, 0, stream>>>(rkvg, state2, tdecay, tfirst, lnxw, lnxb,
                                     state2_out, y);
    k_out<<<1024, 256, 0, stream>>>(Wo, y, x, out);
}

// Round 5
// 319.344 us; speedup vs baseline: 3.1582x; 1.0072x over previous
//
#include <hip/hip_runtime.h>
#include <math.h>

#define D 4096
#define H 64
#define S 64
#define EPS 1e-5f

__device__ __forceinline__ float wave_reduce_sum(float v) {
#pragma unroll
    for (int off = 32; off > 0; off >>= 1) v += __shfl_down(v, off, 64);
    return v;
}

// Async global->LDS, 16B per lane. LDS dest must be wave-uniform (HW adds lane*16);
// global source is per-lane.
__device__ __forceinline__ void gl2lds16(const float* gbase, int lane, float* lds_slot) {
    __builtin_amdgcn_global_load_lds(
        (const __attribute__((address_space(1))) void*)(gbase + lane * 4),
        (__attribute__((address_space(3))) void*)lds_slot, 16, 0, 0);
}

#define WAITV(N) asm volatile("s_waitcnt vmcnt(" #N ")" ::: "memory")
#define WAITL()  asm volatile("s_waitcnt lgkmcnt(0)" ::: "memory")

// ---------------- Kernel 1: LayerNorm(x) -> xx; write state1_out; build 4 mix vectors
__global__ __launch_bounds__(1024) void k_ln_mix(
    const float* __restrict__ x, const float* __restrict__ state1,
    const float* __restrict__ tmk, const float* __restrict__ tmv,
    const float* __restrict__ tmr, const float* __restrict__ tmg,
    const float* __restrict__ ln1w, const float* __restrict__ ln1b,
    float* __restrict__ state1_out, float* __restrict__ mix /* [4][D]: r,k,v,g */) {
    __shared__ float red[32];
    __shared__ float mb[2];
    const int tid = threadIdx.x;
    const float4 xv = ((const float4*)x)[tid];
    float s = (xv.x + xv.y) + (xv.z + xv.w);
    float sq = (xv.x * xv.x + xv.y * xv.y) + (xv.z * xv.z + xv.w * xv.w);
    s = wave_reduce_sum(s);
    sq = wave_reduce_sum(sq);
    const int wave = tid >> 6, lane = tid & 63;
    if (lane == 0) { red[wave] = s; red[16 + wave] = sq; }
    __syncthreads();
    if (tid == 0) {
        float ts = 0.f, tq = 0.f;
        for (int i = 0; i < 16; ++i) { ts += red[i]; tq += red[16 + i]; }
        float m = ts / (float)D;
        float var = tq / (float)D - m * m;
        mb[0] = m;
        mb[1] = rsqrtf(var + EPS);
    }
    __syncthreads();
    const float m = mb[0], rs = mb[1];
    const float4 w4 = ((const float4*)ln1w)[tid];
    const float4 b4 = ((const float4*)ln1b)[tid];
    float4 xx;
    xx.x = (xv.x - m) * rs * w4.x + b4.x;
    xx.y = (xv.y - m) * rs * w4.y + b4.y;
    xx.z = (xv.z - m) * rs * w4.z + b4.z;
    xx.w = (xv.w - m) * rs * w4.w + b4.w;
    ((float4*)state1_out)[tid] = xx;
    const float4 s1 = ((const float4*)state1)[tid];
    float4 d;
    d.x = xx.x - s1.x; d.y = xx.y - s1.y; d.z = xx.z - s1.z; d.w = xx.w - s1.w;
    const float4 tr = ((const float4*)tmr)[tid];
    const float4 tk = ((const float4*)tmk)[tid];
    const float4 tv = ((const float4*)tmv)[tid];
    const float4 tg = ((const float4*)tmg)[tid];
    float4 o;
    o.x = s1.x + d.x * tr.x; o.y = s1.y + d.y * tr.y; o.z = s1.z + d.z * tr.z; o.w = s1.w + d.w * tr.w;
    ((float4*)mix)[tid] = o;
    o.x = s1.x + d.x * tk.x; o.y = s1.y + d.y * tk.y; o.z = s1.z + d.z * tk.z; o.w = s1.w + d.w * tk.w;
    ((float4*)mix)[1024 + tid] = o;
    o.x = s1.x + d.x * tv.x; o.y = s1.y + d.y * tv.y; o.z = s1.z + d.z * tv.z; o.w = s1.w + d.w * tv.w;
    ((float4*)mix)[2048 + tid] = o;
    o.x = s1.x + d.x * tg.x; o.y = s1.y + d.y * tg.y; o.z = s1.z + d.z * tg.z; o.w = s1.w + d.w * tg.w;
    ((float4*)mix)[3072 + tid] = o;
}

// Streamed GEMV step: consume chunk pair C from the wave-private ring,
// then refill the freed slots with pair C+4. vmcnt counted, never 0 mid-loop.
#define GSTEP(C, VC, ISSUE)                                                     \
    {                                                                           \
        WAITV(VC);                                                              \
        __builtin_amdgcn_sched_barrier(0);                                      \
        const float4 w0 = ((const float4*)ring[wave][((C) & 3) * 2])[lane];     \
        const float4 w1 = ((const float4*)ring[wave][((C) & 3) * 2 + 1])[lane]; \
        const float4 xv = ((const float4*)svec)[(C) * 64 + lane];               \
        WAITL(); /* ds_reads landed in VGPRs -> slots reusable */               \
        __builtin_amdgcn_sched_barrier(0);                                      \
        if (ISSUE) {                                                            \
            gl2lds16(w0base + ((C) + 4) * 256, lane, &ring[wave][((C) & 3) * 2][0]);     \
            gl2lds16(w1base + ((C) + 4) * 256, lane, &ring[wave][((C) & 3) * 2 + 1][0]); \
        }                                                                       \
        a0 += w0.x * xv.x + w0.y * xv.y;                                        \
        a1 += w0.z * xv.z + w0.w * xv.w;                                        \
        b0 += w1.x * xv.x + w1.y * xv.y;                                        \
        b1 += w1.z * xv.z + w1.w * xv.w;                                        \
    }

#define GRUN()            \
    GSTEP(0, 6, 1)        \
    GSTEP(1, 6, 1)        \
    GSTEP(2, 6, 1)        \
    GSTEP(3, 6, 1)        \
    GSTEP(4, 6, 1)        \
    GSTEP(5, 6, 1)        \
    GSTEP(6, 6, 1)        \
    GSTEP(7, 6, 1)        \
    GSTEP(8, 6, 1)        \
    GSTEP(9, 6, 1)        \
    GSTEP(10, 6, 1)       \
    GSTEP(11, 6, 1)       \
    GSTEP(12, 6, 0)       \
    GSTEP(13, 4, 0)       \
    GSTEP(14, 2, 0)       \
    GSTEP(15, 0, 0)

// ---------------- Kernel 2: fused 4x GEMV (Wr,Wk,Wv,Wg) @ their mixes -> rkvg[4][D]
// 2 rows per wave, streamed via global_load_lds into an 8-slot/wave LDS ring.
__global__ __launch_bounds__(256) void k_gemv4(
    const float* __restrict__ Wr, const float* __restrict__ Wk,
    const float* __restrict__ Wv, const float* __restrict__ Wg,
    const float* __restrict__ mix, float* __restrict__ rkvg) {
    __shared__ float4 svec[1024];          // mix vector for matrix m (16KB)
    __shared__ float ring[4][8][256];      // per-wave 8-slot x 1KB ring (32KB)
    const int wave = threadIdx.x >> 6, lane = threadIdx.x & 63;
    const int wg = blockIdx.x * 4 + wave;  // 0..8191
    const int m = wg >> 11;                // 2048 waves per matrix
    const int r0 = (wg & 2047) * 2;        // row pair within matrix
    const float* W = (m == 0) ? Wr : (m == 1) ? Wk : (m == 2) ? Wv : Wg;
    const float4* vx = (const float4*)mix + (m << 10);
#pragma unroll
    for (int t = 0; t < 4; ++t) svec[t * 256 + threadIdx.x] = vx[t * 256 + threadIdx.x];
    __syncthreads();                       // also drains vmcnt before the ring stream

    const float* w0base = W + (size_t)r0 * D;
    const float* w1base = w0base + D;
    // prologue: pairs 0..3 -> slots 0..7 (8 outstanding)
#pragma unroll
    for (int p = 0; p < 4; ++p) {
        gl2lds16(w0base + p * 256, lane, &ring[wave][p * 2][0]);
        gl2lds16(w1base + p * 256, lane, &ring[wave][p * 2 + 1][0]);
    }
    float a0 = 0.f, a1 = 0.f, b0 = 0.f, b1 = 0.f;
    GRUN()

    float a = wave_reduce_sum(a0 + a1);
    float b = wave_reduce_sum(b0 + b1);
    if (lane == 0) {
        rkvg[m * D + r0] = a;
        rkvg[m * D + r0 + 1] = b;
    }
}

// ---------------- Kernel 3: per-head kv/wkv/state2 decay + instance norm + SiLU gate -> y
__global__ __launch_bounds__(1024) void k_heads(
    const float* __restrict__ rkvg, const float* __restrict__ state2,
    const float* __restrict__ tdecay, const float* __restrict__ tfirst,
    const float* __restrict__ lnxw, const float* __restrict__ lnxb,
    float* __restrict__ state2_out, float* __restrict__ y) {
    __shared__ float part[16][64];
    const int h = blockIdx.x;
    const int wave = threadIdx.x >> 6, j = threadIdx.x & 63;
    const int base = h * S;
    const float rj = rkvg[base + j];
    const float kj = rkvg[D + base + j];
    const float vj = rkvg[2 * D + base + j];
    const float tfj = tfirst[base + j];
    const float tdj = tdecay[base + j];
    const float* s2 = state2 + (size_t)h * S * S;
    float* s2o = state2_out + (size_t)h * S * S;
    float sv[4];
#pragma unroll
    for (int ii = 0; ii < 4; ++ii) sv[ii] = s2[(wave * 4 + ii) * S + j];
    float wkv = 0.f;
#pragma unroll
    for (int ii = 0; ii < 4; ++ii) {
        const int i = wave * 4 + ii;
        float ri = __shfl(rj, i, 64);
        float ki = __shfl(kj, i, 64);
        float tfi = __shfl(tfj, i, 64);
        float tdi = __shfl(tdj, i, 64);
        float kv = ki * vj;
        wkv += ri * (kv * tfi + sv[ii]);
        s2o[i * S + j] = kv + sv[ii] * tdi;
    }
    part[wave][j] = wkv;
    __syncthreads();
    if (wave == 0) {
        float w0 = 0.f;
#pragma unroll
        for (int t = 0; t < 16; ++t) w0 += part[t][j];
        float sum = w0, sq = w0 * w0;
#pragma unroll
        for (int off = 1; off < 64; off <<= 1) {
            sum += __shfl_xor(sum, off, 64);
            sq += __shfl_xor(sq, off, 64);
        }
        float mu = sum / (float)S;
        float var = sq / (float)S - mu * mu;
        float xn = (w0 - mu) * rsqrtf(var + EPS);
        float gj = rkvg[3 * D + base + j];
        float gate = gj / (1.f + expf(-gj));
        y[base + j] = (xn * lnxw[base + j] + lnxb[base + j]) * gate;
    }
}

// ---------------- Kernel 4: out = x + Wo @ y ; 2 rows per wave, same ring stream
__global__ __launch_bounds__(256) void k_out(
    const float* __restrict__ Wo, const float* __restrict__ y,
    const float* __restrict__ x, float* __restrict__ out) {
    __shared__ float4 svec[1024];          // y (16KB)
    __shared__ float ring[4][8][256];      // 32KB
    const int wave = threadIdx.x >> 6, lane = threadIdx.x & 63;
    const int wg = blockIdx.x * 4 + wave;  // 0..2047
    const int r0 = wg * 2;
    const float4* vy = (const float4*)y;
#pragma unroll
    for (int t = 0; t < 4; ++t) svec[t * 256 + threadIdx.x] = vy[t * 256 + threadIdx.x];
    __syncthreads();

    const float* w0base = Wo + (size_t)r0 * D;
    const float* w1base = w0base + D;
#pragma unroll
    for (int p = 0; p < 4; ++p) {
        gl2lds16(w0base + p * 256, lane, &ring[wave][p * 2][0]);
        gl2lds16(w1base + p * 256, lane, &ring[wave][p * 2 + 1][0]);
    }
    float a0 = 0.f, a1 = 0.f, b0 = 0.f, b1 = 0.f;
    GRUN()

    float a = wave_reduce_sum(a0 + a1);
    float b = wave_reduce_sum(b0 + b1);
    if (lane == 0) {
        out[r0] = x[r0] + a;
        out[r0 + 1] = x[r0 + 1] + b;
    }
}

extern "C" void kernel_launch(void* const* d_in, const int* in_sizes, int n_in,
                              void* d_out, int out_size, void* d_ws, size_t ws_size,
                              hipStream_t stream) {
    const float* x      = (const float*)d_in[0];
    const float* state1 = (const float*)d_in[1];
    const float* state2 = (const float*)d_in[2];
    const float* tmk    = (const float*)d_in[3];
    const float* tmv    = (const float*)d_in[4];
    const float* tmr    = (const float*)d_in[5];
    const float* tmg    = (const float*)d_in[6];
    const float* tdecay = (const float*)d_in[7];
    const float* tfirst = (const float*)d_in[8];
    const float* Wr     = (const float*)d_in[9];
    const float* Wk     = (const float*)d_in[10];
    const float* Wv     = (const float*)d_in[11];
    const float* Wg     = (const float*)d_in[12];
    const float* Wo     = (const float*)d_in[13];
    const float* ln1w   = (const float*)d_in[14];
    const float* ln1b   = (const float*)d_in[15];
    const float* lnxw   = (const float*)d_in[16];
    const float* lnxb   = (const float*)d_in[17];

    float* out        = (float*)d_out;        // [D]
    float* state1_out = out + D;              // [D]
    float* state2_out = out + 2 * D;          // [H*S*S]

    float* mix  = (float*)d_ws;               // [4*D] (r,k,v,g order)
    float* rkvg = mix + 4 * D;                // [4*D]
    float* y    = rkvg + 4 * D;               // [D]

    k_ln_mix<<<1, 1024, 0, stream>>>(x, state1, tmk, tmv, tmr, tmg, ln1w, ln1b,
                                     state1_out, mix);
    k_gemv4<<<2048, 256, 0, stream>>>(Wr, Wk, Wv, Wg, mix, rkvg);
    k_heads<<<64, 1024, 0, stream>>>(rkvg, state2, tdecay, tfirst, lnxw, lnxb,
                                     state2_out, y);
    k_out<<<512, 256, 0, stream>>>(Wo, y, x, out);
}